// Round 1
// baseline (217.566 us; speedup 1.0000x reference)
//
#include <hip/hip_runtime.h>
#include <hip/hip_bf16.h>

// ---- types ----
typedef short bf16x8 __attribute__((ext_vector_type(8)));   // MFMA A/B frag (8 bf16)
typedef float floatx4 __attribute__((ext_vector_type(4)));  // MFMA C/D frag

typedef const __attribute__((address_space(1))) void gvoid_t;
typedef __attribute__((address_space(3))) void lvoid_t;

__device__ __forceinline__ void gload_lds16(const void* g, void* l) {
  // wave-uniform LDS base; HW writes 16B at l + lane*16 per lane
  __builtin_amdgcn_global_load_lds((gvoid_t*)g, (lvoid_t*)l, 16, 0, 0);
}

__device__ __forceinline__ unsigned short f2bf(float f) {
  union { float f; unsigned u; } c; c.f = f;
  unsigned u = c.u + 0x7FFFu + ((c.u >> 16) & 1u);  // RNE
  return (unsigned short)(u >> 16);
}

// ---- sizes ----
// B=8, N=1024, DIM=512, H=8, Dh=64, INNER=512, M=8192
#define SEQ 1024
#define NH  8
#define DH  64

// ================= cast kernels =================
__global__ __launch_bounds__(256) void cast_f32_bf16(const float* __restrict__ in,
                                                     unsigned short* __restrict__ out, int n4) {
  int i = blockIdx.x * blockDim.x + threadIdx.x;
  if (i >= n4) return;
  float4 v = ((const float4*)in)[i];
  ushort4 o;
  o.x = f2bf(v.x); o.y = f2bf(v.y); o.z = f2bf(v.z); o.w = f2bf(v.w);
  ((ushort4*)out)[i] = o;
}

// out[n*K + k] = in[k*N + n]
__global__ __launch_bounds__(256) void tcast_f32_bf16(const float* __restrict__ in,
                                                      unsigned short* __restrict__ out,
                                                      int K, int N) {
  int idx = blockIdx.x * blockDim.x + threadIdx.x;
  if (idx >= K * N) return;
  int k = idx / N, n = idx - k * N;
  out[n * K + k] = f2bf(in[idx]);
}

// ================= GEMM: C[m][n] = sum_k A[m][k] * Bt[n][k] =================
// 128x128 tile, BK=64, 4 waves (2x2 of 64x64), mfma 16x16x32 bf16.
// EPI 0: scatter to q(*0.125)/k/vT bf16 buffers.  EPI 1: f32 out + bias.
template <int EPI>
__global__ __launch_bounds__(256, 2) void gemm_bf16(
    const unsigned short* __restrict__ A,   // [M][K] bf16
    const unsigned short* __restrict__ Bt,  // [N][K] bf16
    int M, int N, int K,
    unsigned short* __restrict__ qo, unsigned short* __restrict__ ko,
    unsigned short* __restrict__ vo,
    float* __restrict__ out, const float* __restrict__ bias) {
  __shared__ alignas(16) unsigned short lA[128 * 64];
  __shared__ alignas(16) unsigned short lB[128 * 64];
  const int tid = threadIdx.x;
  const int wave = tid >> 6, lane = tid & 63;
  const int wr = wave >> 1, wc = wave & 1;
  const int lrow = lane & 15, lk = lane >> 4;
  const int m0 = blockIdx.x * 128, n0 = blockIdx.y * 128;

  floatx4 acc[4][4] = {};

  for (int k0 = 0; k0 < K; k0 += 64) {
    __syncthreads();
#pragma unroll
    for (int i = 0; i < 4; ++i) {
      int c = i * 256 + tid;        // chunk id 0..1023 (16B chunks)
      int row = c >> 3, kc = c & 7;
      int ksw = (kc ^ (row & 7)) << 3;  // pre-swizzled source (elements)
      gload_lds16(A + (size_t)(m0 + row) * K + k0 + ksw,
                  &lA[(i * 256 + wave * 64) * 8]);
      gload_lds16(Bt + (size_t)(n0 + row) * K + k0 + ksw,
                  &lB[(i * 256 + wave * 64) * 8]);
    }
    __syncthreads();
#pragma unroll
    for (int f = 0; f < 2; ++f) {
      bf16x8 av[4], bv[4];
      int kc = lk + f * 4;
#pragma unroll
      for (int mt = 0; mt < 4; ++mt) {
        int r = wr * 64 + mt * 16 + lrow;
        av[mt] = *(const bf16x8*)&lA[r * 64 + ((kc ^ (r & 7)) << 3)];
      }
#pragma unroll
      for (int nt = 0; nt < 4; ++nt) {
        int r = wc * 64 + nt * 16 + lrow;
        bv[nt] = *(const bf16x8*)&lB[r * 64 + ((kc ^ (r & 7)) << 3)];
      }
#pragma unroll
      for (int mt = 0; mt < 4; ++mt)
#pragma unroll
        for (int nt = 0; nt < 4; ++nt)
          acc[mt][nt] = __builtin_amdgcn_mfma_f32_16x16x32_bf16(av[mt], bv[nt], acc[mt][nt], 0, 0, 0);
    }
  }

  // epilogue: C element (m, n) at acc[mt][nt][reg]; row=(lane>>4)*4+reg, col=lane&15
#pragma unroll
  for (int mt = 0; mt < 4; ++mt)
#pragma unroll
    for (int nt = 0; nt < 4; ++nt)
#pragma unroll
      for (int rg = 0; rg < 4; ++rg) {
        int m = m0 + wr * 64 + mt * 16 + lk * 4 + rg;
        int n = n0 + wc * 64 + nt * 16 + lrow;
        float v = acc[mt][nt][rg];
        if constexpr (EPI == 0) {
          int b = m >> 10, ii = m & 1023;
          int sect = n >> 9, r = n & 511;
          int h = r >> 6, d = r & 63;
          size_t bh = (size_t)((b << 3) + h);
          if (sect == 0)      qo[bh * 65536 + (size_t)ii * 64 + d] = f2bf(v * 0.125f);
          else if (sect == 1) ko[bh * 65536 + (size_t)ii * 64 + d] = f2bf(v);
          else                vo[bh * 65536 + (size_t)d * 1024 + ii] = f2bf(v);
        } else {
          out[(size_t)m * N + n] = v + bias[n];
        }
      }
}

// ================= flash attention =================
// grid: 1024 blocks = 64 (b,h) * 16 q-tiles; 4 waves, each owns 16 q-rows.
__global__ __launch_bounds__(256, 2) void attn_kernel(
    const unsigned short* __restrict__ q,    // [64][1024][64] bf16, pre-scaled by 1/8
    const unsigned short* __restrict__ kbuf, // [64][1024][64] bf16
    const unsigned short* __restrict__ vT,   // [64][64][1024] bf16
    const float* __restrict__ btab,          // [2047][8] f32
    unsigned short* __restrict__ ao)         // [8][1024][512] bf16
{
  __shared__ alignas(16) unsigned short lK[64 * 64];
  __shared__ alignas(16) unsigned short lV[64 * 64];
  __shared__ alignas(16) unsigned short lP[4 * 16 * 64];
  const int tid = threadIdx.x, wave = tid >> 6, lane = tid & 63;
  const int lrow = lane & 15, lk = lane >> 4;
  const int blk = blockIdx.x;
  const int bh = blk >> 4, qt = blk & 15;
  const int h = bh & 7, b = bh >> 3;
  const int q0 = qt * 64 + wave * 16;  // first q-row of this wave
  const size_t base = (size_t)bh * 65536;
  unsigned short* lPw = lP + wave * 1024;

  bf16x8 qf[2];
#pragma unroll
  for (int f = 0; f < 2; ++f)
    qf[f] = *(const bf16x8*)(q + base + (size_t)(q0 + lrow) * 64 + lk * 8 + f * 32);

  floatx4 accO[4] = {};
  float mrow[4], srow[4];
#pragma unroll
  for (int rg = 0; rg < 4; ++rg) { mrow[rg] = -1e30f; srow[rg] = 0.f; }

  for (int t = 0; t < 16; ++t) {
    const int j0 = t * 64;
    __syncthreads();  // previous iter's LDS reads done
#pragma unroll
    for (int i = 0; i < 2; ++i) {
      int c = i * 256 + tid;
      int row = c >> 3, kc = c & 7;
      int ksw = (kc ^ (row & 7)) << 3;
      gload_lds16(kbuf + base + (size_t)(j0 + row) * 64 + ksw,
                  &lK[(i * 256 + wave * 64) * 8]);
      gload_lds16(vT + base + (size_t)row * 1024 + j0 + ksw,
                  &lV[(i * 256 + wave * 64) * 8]);
    }
    __syncthreads();

    // QK^T: st[jt] covers cols jt*16..+15 of this KV tile for 16 q-rows
    floatx4 st[4] = {};
#pragma unroll
    for (int f = 0; f < 2; ++f) {
      int kc = lk + f * 4;
#pragma unroll
      for (int jt = 0; jt < 4; ++jt) {
        int r = jt * 16 + lrow;
        bf16x8 kf = *(const bf16x8*)&lK[r * 64 + ((kc ^ (r & 7)) << 3)];
        st[jt] = __builtin_amdgcn_mfma_f32_16x16x32_bf16(qf[f], kf, st[jt], 0, 0, 0);
      }
    }
    // + relative bias
#pragma unroll
    for (int jt = 0; jt < 4; ++jt)
#pragma unroll
      for (int rg = 0; rg < 4; ++rg) {
        int i_ = q0 + lk * 4 + rg;
        int j = j0 + jt * 16 + lrow;
        st[jt][rg] += btab[(i_ - j + 1023) * 8 + h];
      }
    // online softmax (row = lk*4+rg, 16 lanes per row-group hold 16 cols each tile)
    float nm[4], fs[4], rs[4];
#pragma unroll
    for (int rg = 0; rg < 4; ++rg) {
      float pm = fmaxf(fmaxf(st[0][rg], st[1][rg]), fmaxf(st[2][rg], st[3][rg]));
#pragma unroll
      for (int msk = 1; msk < 16; msk <<= 1) pm = fmaxf(pm, __shfl_xor(pm, msk));
      nm[rg] = fmaxf(mrow[rg], pm);
      fs[rg] = exp2f((mrow[rg] - nm[rg]) * 1.44269504f);
      mrow[rg] = nm[rg];
      rs[rg] = 0.f;
    }
#pragma unroll
    for (int jt = 0; jt < 4; ++jt)
#pragma unroll
      for (int rg = 0; rg < 4; ++rg) {
        float p = exp2f((st[jt][rg] - nm[rg]) * 1.44269504f);
        rs[rg] += p;
        int row = lk * 4 + rg;
        int col = jt * 16 + lrow;
        lPw[row * 64 + (((col >> 3) ^ (row & 7)) << 3) + (col & 7)] = f2bf(p);
      }
#pragma unroll
    for (int rg = 0; rg < 4; ++rg) {
      float s = rs[rg];
#pragma unroll
      for (int msk = 1; msk < 16; msk <<= 1) s += __shfl_xor(s, msk);
      srow[rg] = srow[rg] * fs[rg] + s;
    }
#pragma unroll
    for (int dt = 0; dt < 4; ++dt)
#pragma unroll
      for (int rg = 0; rg < 4; ++rg) accO[dt][rg] *= fs[rg];

    __syncthreads();  // P visible (safe cross-lane ordering)

    // PV: out[i][d] += P[i][j] * V[j][d]  (B-frag from vT rows = d)
#pragma unroll
    for (int f = 0; f < 2; ++f) {
      int kc = lk + f * 4;
      bf16x8 pf = *(const bf16x8*)&lPw[lrow * 64 + ((kc ^ (lrow & 7)) << 3)];
#pragma unroll
      for (int dt = 0; dt < 4; ++dt) {
        int r = dt * 16 + lrow;
        bf16x8 vf = *(const bf16x8*)&lV[r * 64 + ((kc ^ (r & 7)) << 3)];
        accO[dt] = __builtin_amdgcn_mfma_f32_16x16x32_bf16(pf, vf, accO[dt], 0, 0, 0);
      }
    }
  }

  // epilogue: ao[b][i][h*64 + d]
#pragma unroll
  for (int dt = 0; dt < 4; ++dt)
#pragma unroll
    for (int rg = 0; rg < 4; ++rg) {
      int i_ = q0 + lk * 4 + rg;
      float v = accO[dt][rg] / srow[rg];
      ao[(size_t)(b * 1024 + i_) * 512 + h * 64 + dt * 16 + lrow] = f2bf(v);
    }
}

// ================= launch =================
extern "C" void kernel_launch(void* const* d_in, const int* in_sizes, int n_in,
                              void* d_out, int out_size, void* d_ws, size_t ws_size,
                              hipStream_t stream) {
  (void)in_sizes; (void)n_in; (void)out_size; (void)ws_size;
  const float* x      = (const float*)d_in[0];  // [8,1024,512]
  const float* w_qkv  = (const float*)d_in[1];  // [512,1536]
  const float* btab   = (const float*)d_in[2];  // [2047,8]
  const float* w_out  = (const float*)d_in[3];  // [512,512]
  const float* b_out  = (const float*)d_in[4];  // [512]
  float* out = (float*)d_out;

  char* ws = (char*)d_ws;
  unsigned short* xb    = (unsigned short*)(ws);             // 8192*512 bf16
  unsigned short* wqkvT = (unsigned short*)(ws + 8388608);   // [1536][512]
  unsigned short* woutT = (unsigned short*)(ws + 9961472);   // [512][512]
  unsigned short* qb    = (unsigned short*)(ws + 10485760);  // [64][1024][64]
  unsigned short* kb    = (unsigned short*)(ws + 18874368);  // [64][1024][64]
  unsigned short* vT    = (unsigned short*)(ws + 27262976);  // [64][64][1024]
  unsigned short* ao    = (unsigned short*)(ws + 35651584);  // [8192][512]

  hipLaunchKernelGGL(cast_f32_bf16, dim3(4096), dim3(256), 0, stream, x, xb, 1048576);
  hipLaunchKernelGGL(tcast_f32_bf16, dim3(3072), dim3(256), 0, stream, w_qkv, wqkvT, 512, 1536);
  hipLaunchKernelGGL(tcast_f32_bf16, dim3(1024), dim3(256), 0, stream, w_out, woutT, 512, 512);

  hipLaunchKernelGGL((gemm_bf16<0>), dim3(64, 12), dim3(256), 0, stream,
                     xb, wqkvT, 8192, 1536, 512, qb, kb, vT, (float*)nullptr, (const float*)nullptr);

  hipLaunchKernelGGL(attn_kernel, dim3(1024), dim3(256), 0, stream, qb, kb, vT, btab, ao);

  hipLaunchKernelGGL((gemm_bf16<1>), dim3(64, 4), dim3(256), 0, stream,
                     ao, woutT, 8192, 512, 512,
                     (unsigned short*)nullptr, (unsigned short*)nullptr, (unsigned short*)nullptr,
                     out, b_out);
}

// Round 2
// 128.951 us; speedup vs baseline: 1.6872x; 1.6872x over previous
//
#include <hip/hip_runtime.h>
#include <hip/hip_bf16.h>

// ---- types ----
typedef short bf16x8 __attribute__((ext_vector_type(8)));   // MFMA A/B frag (8 bf16)
typedef float floatx4 __attribute__((ext_vector_type(4)));  // MFMA C/D frag

typedef const __attribute__((address_space(1))) void gvoid_t;
typedef __attribute__((address_space(3))) void lvoid_t;

__device__ __forceinline__ void gload_lds16(const void* g, void* l) {
  // wave-uniform LDS base; HW writes 16B at l + lane*16 per lane
  __builtin_amdgcn_global_load_lds((gvoid_t*)g, (lvoid_t*)l, 16, 0, 0);
}

__device__ __forceinline__ unsigned short f2bf(float f) {
  union { float f; unsigned u; } c; c.f = f;
  unsigned u = c.u + 0x7FFFu + ((c.u >> 16) & 1u);  // RNE
  return (unsigned short)(u >> 16);
}

#define LOG2E 1.44269504f

// ================= cast kernels =================
__global__ __launch_bounds__(256) void cast_f32_bf16(const float* __restrict__ in,
                                                     unsigned short* __restrict__ out, int n4) {
  int i = blockIdx.x * blockDim.x + threadIdx.x;
  if (i >= n4) return;
  float4 v = ((const float4*)in)[i];
  ushort4 o;
  o.x = f2bf(v.x); o.y = f2bf(v.y); o.z = f2bf(v.z); o.w = f2bf(v.w);
  ((ushort4*)out)[i] = o;
}

// out[n*K + k] = in[k*N + n]
__global__ __launch_bounds__(256) void tcast_f32_bf16(const float* __restrict__ in,
                                                      unsigned short* __restrict__ out,
                                                      int K, int N) {
  int idx = blockIdx.x * blockDim.x + threadIdx.x;
  if (idx >= K * N) return;
  int k = idx / N, n = idx - k * N;
  out[n * K + k] = f2bf(in[idx]);
}

// btT[h][idx] = btab[idx][h] * log2(e)   (fold exp2 domain into the table)
__global__ __launch_bounds__(256) void tbias_kernel(const float* __restrict__ btab,
                                                    float* __restrict__ btT) {
  int i = blockIdx.x * blockDim.x + threadIdx.x;
  if (i >= 2047 * 8) return;
  int idx = i >> 3, h = i & 7;
  btT[h * 2047 + idx] = btab[i] * LOG2E;
}

// ================= GEMM: C[m][n] = sum_k A[m][k] * Bt[n][k] =================
// 128x128 tile, BK=64, 4 waves (2x2 of 64x64), mfma 16x16x32 bf16.
// EPI 0: scatter to q(*scale*log2e)/k/vT bf16 buffers.  EPI 1: f32 out + bias.
template <int EPI>
__global__ __launch_bounds__(256, 2) void gemm_bf16(
    const unsigned short* __restrict__ A,   // [M][K] bf16
    const unsigned short* __restrict__ Bt,  // [N][K] bf16
    int M, int N, int K,
    unsigned short* __restrict__ qo, unsigned short* __restrict__ ko,
    unsigned short* __restrict__ vo,
    float* __restrict__ out, const float* __restrict__ bias) {
  __shared__ alignas(16) unsigned short lA[128 * 64];
  __shared__ alignas(16) unsigned short lB[128 * 64];
  const int tid = threadIdx.x;
  const int wave = tid >> 6, lane = tid & 63;
  const int wr = wave >> 1, wc = wave & 1;
  const int lrow = lane & 15, lk = lane >> 4;
  const int m0 = blockIdx.x * 128, n0 = blockIdx.y * 128;

  floatx4 acc[4][4] = {};

  for (int k0 = 0; k0 < K; k0 += 64) {
    __syncthreads();
#pragma unroll
    for (int i = 0; i < 4; ++i) {
      int c = i * 256 + tid;        // chunk id 0..1023 (16B chunks)
      int row = c >> 3, kc = c & 7;
      int ksw = (kc ^ (row & 7)) << 3;  // pre-swizzled source (elements)
      gload_lds16(A + (size_t)(m0 + row) * K + k0 + ksw,
                  &lA[(i * 256 + wave * 64) * 8]);
      gload_lds16(Bt + (size_t)(n0 + row) * K + k0 + ksw,
                  &lB[(i * 256 + wave * 64) * 8]);
    }
    __syncthreads();
#pragma unroll
    for (int f = 0; f < 2; ++f) {
      bf16x8 av[4], bv[4];
      int kc = lk + f * 4;
#pragma unroll
      for (int mt = 0; mt < 4; ++mt) {
        int r = wr * 64 + mt * 16 + lrow;
        av[mt] = *(const bf16x8*)&lA[r * 64 + ((kc ^ (r & 7)) << 3)];
      }
#pragma unroll
      for (int nt = 0; nt < 4; ++nt) {
        int r = wc * 64 + nt * 16 + lrow;
        bv[nt] = *(const bf16x8*)&lB[r * 64 + ((kc ^ (r & 7)) << 3)];
      }
#pragma unroll
      for (int mt = 0; mt < 4; ++mt)
#pragma unroll
        for (int nt = 0; nt < 4; ++nt)
          acc[mt][nt] = __builtin_amdgcn_mfma_f32_16x16x32_bf16(av[mt], bv[nt], acc[mt][nt], 0, 0, 0);
    }
  }

  // epilogue: C element (m, n) at acc[mt][nt][reg]; row=(lane>>4)*4+reg, col=lane&15
#pragma unroll
  for (int mt = 0; mt < 4; ++mt)
#pragma unroll
    for (int nt = 0; nt < 4; ++nt)
#pragma unroll
      for (int rg = 0; rg < 4; ++rg) {
        int m = m0 + wr * 64 + mt * 16 + lk * 4 + rg;
        int n = n0 + wc * 64 + nt * 16 + lrow;
        float v = acc[mt][nt][rg];
        if constexpr (EPI == 0) {
          int b = m >> 10, ii = m & 1023;
          int sect = n >> 9, r = n & 511;
          int h = r >> 6, d = r & 63;
          size_t bh = (size_t)((b << 3) + h);
          if (sect == 0)      qo[bh * 65536 + (size_t)ii * 64 + d] = f2bf(v * (0.125f * LOG2E));
          else if (sect == 1) ko[bh * 65536 + (size_t)ii * 64 + d] = f2bf(v);
          else                vo[bh * 65536 + (size_t)d * 1024 + ii] = f2bf(v);
        } else {
          out[(size_t)m * N + n] = v + bias[n];
        }
      }
}

// ================= flash attention (swapped QK^T, per-lane softmax) ==========
// grid: 1024 blocks = 64 (b,h) * 16 q-tiles; 4 waves, each owns 16 q-rows.
// st[jt][rg] = S^T[j][i]: j = j0 + jt*16 + lk*4 + rg, i = q0 + lrow.
__global__ __launch_bounds__(256, 4) void attn_kernel(
    const unsigned short* __restrict__ q,    // [64][1024][64] bf16, pre-scaled by 0.125*log2e
    const unsigned short* __restrict__ kbuf, // [64][1024][64] bf16
    const unsigned short* __restrict__ vT,   // [64][64][1024] bf16
    const float* __restrict__ btT,           // [8][2047] f32, pre-scaled by log2e
    unsigned short* __restrict__ ao)         // [8][1024][512] bf16
{
  __shared__ alignas(16) unsigned short lK[2][64 * 64];
  __shared__ alignas(16) unsigned char lPb[4 * 2048];   // per-wave 16 rows x 128B, XOR-swizzled
  __shared__ float lbias[1088];
  const int tid = threadIdx.x, wave = tid >> 6, lane = tid & 63;
  const int lrow = lane & 15, lk = lane >> 4;
  // XCD-bijective swizzle: all 16 q-tiles of 8 bh land on one XCD's L2
  const int lid = ((blockIdx.x & 7) << 7) | (blockIdx.x >> 3);
  const int bh = lid >> 4, qt = lid & 15;
  const int h = bh & 7, b = bh >> 3;
  const int qB = qt * 64;
  const int q0 = qB + wave * 16;           // first q-row of this wave
  const size_t base = (size_t)bh * 65536;
  const unsigned short* vrow = vT + base;  // [64][1024]
  unsigned char* lPw = lPb + wave * 2048 + lrow * 128;
  const int msw = (lrow & 7) << 4;

  // stage bias window [qB, qB+1086] -> lbias
  for (int t = tid; t < 1087; t += 256)
    lbias[t] = btT[h * 2047 + qB + t];

  // Q fragment (B-operand): q[i=q0+lrow][d = lk*8 + f*32 .. +7]
  bf16x8 qf[2];
#pragma unroll
  for (int f = 0; f < 2; ++f)
    qf[f] = *(const bf16x8*)(q + base + (size_t)(q0 + lrow) * 64 + lk * 8 + f * 32);

  // prologue: stage K tile 0 into buf 0
  {
#pragma unroll
    for (int i = 0; i < 2; ++i) {
      int c = i * 256 + tid;
      int row = c >> 3, kc = c & 7;
      int ksw = (kc ^ (row & 7)) << 3;
      gload_lds16(kbuf + base + (size_t)row * 64 + ksw, &lK[0][(i * 256 + wave * 64) * 8]);
    }
  }
  __syncthreads();

  floatx4 accO[4] = {};
  float mrow = -1e30f, srow = 0.f;
  const int bias_base = wave * 16 + lrow + 1023 - lk * 4;
  int buf = 0;

  for (int t = 0; t < 16; ++t) {
    const int j0 = t * 64;
    // stage next K tile into buf^1 (overlaps with this tile's compute)
    if (t < 15) {
      const int jn = j0 + 64;
#pragma unroll
      for (int i = 0; i < 2; ++i) {
        int c = i * 256 + tid;
        int row = c >> 3, kc = c & 7;
        int ksw = (kc ^ (row & 7)) << 3;
        gload_lds16(kbuf + base + (size_t)(jn + row) * 64 + ksw,
                    &lK[buf ^ 1][(i * 256 + wave * 64) * 8]);
      }
    }
    // V fragments direct from global (L1/L2-resident), issued early to hide latency
    bf16x8 vf[2][4];
#pragma unroll
    for (int f = 0; f < 2; ++f)
#pragma unroll
      for (int dt = 0; dt < 4; ++dt)
        vf[f][dt] = *(const bf16x8*)(vrow + (size_t)(dt * 16 + lrow) * 1024 + j0 + f * 32 + lk * 8);

    // QK^T (swapped): st[jt] = S^T rows j=jt*16.., cols i
    floatx4 st[4] = {};
#pragma unroll
    for (int f = 0; f < 2; ++f) {
      int kc = lk + f * 4;
#pragma unroll
      for (int jt = 0; jt < 4; ++jt) {
        int r = jt * 16 + lrow;
        bf16x8 kf = *(const bf16x8*)&lK[buf][r * 64 + ((kc ^ (r & 7)) << 3)];
        st[jt] = __builtin_amdgcn_mfma_f32_16x16x32_bf16(kf, qf[f], st[jt], 0, 0, 0);
      }
    }
    // + relative bias from LDS (log2e-scaled)
    {
      const int bb = bias_base - j0;
#pragma unroll
      for (int jt = 0; jt < 4; ++jt)
#pragma unroll
        for (int rg = 0; rg < 4; ++rg)
          st[jt][rg] += lbias[bb - jt * 16 - rg];
    }
    // online softmax, per-lane scalar stats (i = q0+lrow fixed per lane)
    float pm = st[0][0];
#pragma unroll
    for (int jt = 0; jt < 4; ++jt)
#pragma unroll
      for (int rg = 0; rg < 4; ++rg) pm = fmaxf(pm, st[jt][rg]);
    pm = fmaxf(pm, __shfl_xor(pm, 16));
    pm = fmaxf(pm, __shfl_xor(pm, 32));
    const float nm = fmaxf(mrow, pm);
    const float fs = exp2f(mrow - nm);
    mrow = nm;
    float rs = 0.f;
#pragma unroll
    for (int jt = 0; jt < 4; ++jt)
#pragma unroll
      for (int rg = 0; rg < 4; ++rg) {
        float p = exp2f(st[jt][rg] - nm);
        st[jt][rg] = p;
        rs += p;
      }
    rs += __shfl_xor(rs, 16);
    rs += __shfl_xor(rs, 32);
    srow = srow * fs + rs;
#pragma unroll
    for (int dt = 0; dt < 4; ++dt)
#pragma unroll
      for (int rg = 0; rg < 4; ++rg) accO[dt][rg] *= fs;

    // pack P -> bf16 pairs, write to per-wave swizzled LDS (no barrier needed)
#pragma unroll
    for (int jt = 0; jt < 4; ++jt)
#pragma unroll
      for (int h2 = 0; h2 < 2; ++h2) {
        unsigned pk = ((unsigned)f2bf(st[jt][2 * h2 + 1]) << 16) | f2bf(st[jt][2 * h2]);
        *(unsigned*)(lPw + (((jt * 32 + lk * 8 + h2 * 4)) ^ msw)) = pk;
      }

    // PV: O^T[d][i] += V^T[d][j] * P[j][i]
#pragma unroll
    for (int f = 0; f < 2; ++f) {
      bf16x8 pf = *(const bf16x8*)(lPw + ((f * 64 + lk * 16) ^ msw));
#pragma unroll
      for (int dt = 0; dt < 4; ++dt)
        accO[dt] = __builtin_amdgcn_mfma_f32_16x16x32_bf16(vf[f][dt], pf, accO[dt], 0, 0, 0);
    }

    __syncthreads();  // K stage for t+1 complete; all waves done with lK[buf]
    buf ^= 1;
  }

  // epilogue: accO[dt][rg] = O^T[d = dt*16 + lk*4 + rg][i = q0+lrow]
  const float inv = 1.0f / srow;
  const int i_ = q0 + lrow;
  unsigned short* aor = ao + (size_t)(b * 1024 + i_) * 512 + h * 64 + lk * 4;
#pragma unroll
  for (int dt = 0; dt < 4; ++dt) {
    ushort4 o;
    o.x = f2bf(accO[dt][0] * inv);
    o.y = f2bf(accO[dt][1] * inv);
    o.z = f2bf(accO[dt][2] * inv);
    o.w = f2bf(accO[dt][3] * inv);
    *(ushort4*)(aor + dt * 16) = o;
  }
}

// ================= launch =================
extern "C" void kernel_launch(void* const* d_in, const int* in_sizes, int n_in,
                              void* d_out, int out_size, void* d_ws, size_t ws_size,
                              hipStream_t stream) {
  (void)in_sizes; (void)n_in; (void)out_size; (void)ws_size;
  const float* x      = (const float*)d_in[0];  // [8,1024,512]
  const float* w_qkv  = (const float*)d_in[1];  // [512,1536]
  const float* btab   = (const float*)d_in[2];  // [2047,8]
  const float* w_out  = (const float*)d_in[3];  // [512,512]
  const float* b_out  = (const float*)d_in[4];  // [512]
  float* out = (float*)d_out;

  char* ws = (char*)d_ws;
  unsigned short* xb    = (unsigned short*)(ws);             // 8192*512 bf16
  unsigned short* wqkvT = (unsigned short*)(ws + 8388608);   // [1536][512]
  unsigned short* woutT = (unsigned short*)(ws + 9961472);   // [512][512]
  unsigned short* qb    = (unsigned short*)(ws + 10485760);  // [64][1024][64]
  unsigned short* kb    = (unsigned short*)(ws + 18874368);  // [64][1024][64]
  unsigned short* vT    = (unsigned short*)(ws + 27262976);  // [64][64][1024]
  unsigned short* ao    = (unsigned short*)(ws + 35651584);  // [8192][512]
  float*          btT   = (float*)(ws + 44040192);           // [8][2047] f32

  hipLaunchKernelGGL(cast_f32_bf16, dim3(4096), dim3(256), 0, stream, x, xb, 1048576);
  hipLaunchKernelGGL(tcast_f32_bf16, dim3(3072), dim3(256), 0, stream, w_qkv, wqkvT, 512, 1536);
  hipLaunchKernelGGL(tcast_f32_bf16, dim3(1024), dim3(256), 0, stream, w_out, woutT, 512, 512);
  hipLaunchKernelGGL(tbias_kernel, dim3(64), dim3(256), 0, stream, btab, btT);

  hipLaunchKernelGGL((gemm_bf16<0>), dim3(64, 12), dim3(256), 0, stream,
                     xb, wqkvT, 8192, 1536, 512, qb, kb, vT, (float*)nullptr, (const float*)nullptr);

  hipLaunchKernelGGL(attn_kernel, dim3(1024), dim3(256), 0, stream, qb, kb, vT, btT, ao);

  hipLaunchKernelGGL((gemm_bf16<1>), dim3(64, 4), dim3(256), 0, stream,
                     ao, woutT, 8192, 512, 512,
                     (unsigned short*)nullptr, (unsigned short*)nullptr, (unsigned short*)nullptr,
                     out, b_out);
}

// Round 6
// 108.898 us; speedup vs baseline: 1.9979x; 1.1841x over previous
//
#include <hip/hip_runtime.h>
#include <hip/hip_bf16.h>

// ---- types ----
typedef short bf16x8 __attribute__((ext_vector_type(8)));    // MFMA A/B frag (8 bf16)
typedef float floatx4 __attribute__((ext_vector_type(4)));   // 16x16 MFMA C/D frag
typedef float floatx16 __attribute__((ext_vector_type(16))); // 32x32 MFMA C/D frag
typedef unsigned uintx4 __attribute__((ext_vector_type(4)));

typedef const __attribute__((address_space(1))) void gvoid_t;
typedef __attribute__((address_space(3))) void lvoid_t;

__device__ __forceinline__ void gload_lds16(const void* g, void* l) {
  // wave-uniform LDS base; HW writes 16B at l + lane*16 per lane
  __builtin_amdgcn_global_load_lds((gvoid_t*)g, (lvoid_t*)l, 16, 0, 0);
}

__device__ __forceinline__ unsigned short f2bf(float f) {
  union { float f; unsigned u; } c; c.f = f;
  unsigned u = c.u + 0x7FFFu + ((c.u >> 16) & 1u);  // RNE
  return (unsigned short)(u >> 16);
}

#define LOG2E 1.44269504f

// ================= cast kernels =================
__global__ __launch_bounds__(256) void cast_f32_bf16(const float* __restrict__ in,
                                                     unsigned short* __restrict__ out, int n4) {
  int i = blockIdx.x * blockDim.x + threadIdx.x;
  if (i >= n4) return;
  float4 v = ((const float4*)in)[i];
  ushort4 o;
  o.x = f2bf(v.x); o.y = f2bf(v.y); o.z = f2bf(v.z); o.w = f2bf(v.w);
  ((ushort4*)out)[i] = o;
}

// out[n*K + k] = in[k*N + n]
__global__ __launch_bounds__(256) void tcast_f32_bf16(const float* __restrict__ in,
                                                      unsigned short* __restrict__ out,
                                                      int K, int N) {
  int idx = blockIdx.x * blockDim.x + threadIdx.x;
  if (idx >= K * N) return;
  int k = idx / N, n = idx - k * N;
  out[n * K + k] = f2bf(in[idx]);
}

// btT[h][idx] = btab[idx][h] * log2(e)   (fold exp2 domain into the table)
__global__ __launch_bounds__(256) void tbias_kernel(const float* __restrict__ btab,
                                                    float* __restrict__ btT) {
  int i = blockIdx.x * blockDim.x + threadIdx.x;
  if (i >= 2047 * 8) return;
  int idx = i >> 3, h = i & 7;
  btT[h * 2047 + idx] = btab[i] * LOG2E;
}

// ================= GEMM: C[m][n] = sum_k A[m][k] * Bt[n][k] =================
// 128x128 tile, BK=64, 4 waves (2x2 of 64x64), mfma 16x16x32 bf16.
template <int EPI>
__global__ __launch_bounds__(256, 2) void gemm_bf16(
    const unsigned short* __restrict__ A,   // [M][K] bf16
    const unsigned short* __restrict__ Bt,  // [N][K] bf16
    int M, int N, int K,
    unsigned short* __restrict__ qo, unsigned short* __restrict__ ko,
    unsigned short* __restrict__ vo,
    float* __restrict__ out, const float* __restrict__ bias) {
  __shared__ alignas(16) unsigned short lA[128 * 64];
  __shared__ alignas(16) unsigned short lB[128 * 64];
  const int tid = threadIdx.x;
  const int wave = tid >> 6, lane = tid & 63;
  const int wr = wave >> 1, wc = wave & 1;
  const int lrow = lane & 15, lk = lane >> 4;
  const int m0 = blockIdx.x * 128, n0 = blockIdx.y * 128;

  floatx4 acc[4][4] = {};

  for (int k0 = 0; k0 < K; k0 += 64) {
    __syncthreads();
#pragma unroll
    for (int i = 0; i < 4; ++i) {
      int c = i * 256 + tid;        // chunk id 0..1023 (16B chunks)
      int row = c >> 3, kc = c & 7;
      int ksw = (kc ^ (row & 7)) << 3;  // pre-swizzled source (elements)
      gload_lds16(A + (size_t)(m0 + row) * K + k0 + ksw,
                  &lA[(i * 256 + wave * 64) * 8]);
      gload_lds16(Bt + (size_t)(n0 + row) * K + k0 + ksw,
                  &lB[(i * 256 + wave * 64) * 8]);
    }
    __syncthreads();
#pragma unroll
    for (int f = 0; f < 2; ++f) {
      bf16x8 av[4], bv[4];
      int kc = lk + f * 4;
#pragma unroll
      for (int mt = 0; mt < 4; ++mt) {
        int r = wr * 64 + mt * 16 + lrow;
        av[mt] = *(const bf16x8*)&lA[r * 64 + ((kc ^ (r & 7)) << 3)];
      }
#pragma unroll
      for (int nt = 0; nt < 4; ++nt) {
        int r = wc * 64 + nt * 16 + lrow;
        bv[nt] = *(const bf16x8*)&lB[r * 64 + ((kc ^ (r & 7)) << 3)];
      }
#pragma unroll
      for (int mt = 0; mt < 4; ++mt)
#pragma unroll
        for (int nt = 0; nt < 4; ++nt)
          acc[mt][nt] = __builtin_amdgcn_mfma_f32_16x16x32_bf16(av[mt], bv[nt], acc[mt][nt], 0, 0, 0);
    }
  }

#pragma unroll
  for (int mt = 0; mt < 4; ++mt)
#pragma unroll
    for (int nt = 0; nt < 4; ++nt)
#pragma unroll
      for (int rg = 0; rg < 4; ++rg) {
        int m = m0 + wr * 64 + mt * 16 + lk * 4 + rg;
        int n = n0 + wc * 64 + nt * 16 + lrow;
        float v = acc[mt][nt][rg];
        if constexpr (EPI == 0) {
          int b = m >> 10, ii = m & 1023;
          int sect = n >> 9, r = n & 511;
          int h = r >> 6, d = r & 63;
          size_t bh = (size_t)((b << 3) + h);
          if (sect == 0)      qo[bh * 65536 + (size_t)ii * 64 + d] = f2bf(v * (0.125f * LOG2E));
          else if (sect == 1) ko[bh * 65536 + (size_t)ii * 64 + d] = f2bf(v);
          else                vo[bh * 65536 + (size_t)d * 1024 + ii] = f2bf(v);
        } else {
          out[(size_t)m * N + n] = v + bias[n];
        }
      }
}

// ================= flash attention, 32x32 MFMA, in-register softmax ==========
// grid: 1024 blocks = 64 (b,h) * 16 q-tiles(64 rows); 2 waves, 32 q-rows each.
// Swapped QK^T: st0/st1 reg r holds S^T[j][i], j = jb*32+(r&3)+8*(r>>2)+4*hi,
// i = base + (lane&31).  Softmax per-lane; all lane^32 exchanges via shfl_xor
// (round-4/5 lesson: "+v","+v" inline-asm permlane on two copies of the SAME
// value can be register-coalesced into a self-swap -> silent corruption).
__global__ __launch_bounds__(128, 2) void attn_kernel(
    const unsigned short* __restrict__ q,    // [64][1024][64] bf16, pre-scaled 0.125*log2e
    const unsigned short* __restrict__ kbuf, // [64][1024][64] bf16
    const unsigned short* __restrict__ vT,   // [64][64][1024] bf16
    const float* __restrict__ btT,           // [8][2047] f32, pre-scaled log2e
    unsigned short* __restrict__ ao)         // [8][1024][512] bf16
{
  __shared__ alignas(16) unsigned short lK[2][64 * 64];
  __shared__ float lbias[1088];
  const int tid = threadIdx.x, wave = tid >> 6, lane = tid & 63;
  const int il = lane & 31, hi = lane >> 5;
  // XCD-bijective swizzle: all 16 q-tiles of 8 bh land on one XCD's L2
  const int lid = ((blockIdx.x & 7) << 7) | (blockIdx.x >> 3);
  const int bh = lid >> 4, qt = lid & 15;
  const int h = bh & 7, b = bh >> 3;
  const int qB = qt * 64;
  const int i_ = qB + wave * 32 + il;      // this lane's q-row
  const size_t base = (size_t)bh * 65536;
  const unsigned short* vrow = vT + base;  // [64][1024]

  // stage bias window [qB, qB+1086] -> lbias
  for (int t = tid; t < 1087; t += 128)
    lbias[t] = btT[h * 2047 + qB + t];

  // Q frags (B-operand): Q[i_][kd*16 + hi*8 + e]
  bf16x8 qf[4];
#pragma unroll
  for (int kd = 0; kd < 4; ++kd)
    qf[kd] = *(const bf16x8*)(q + base + (size_t)i_ * 64 + kd * 16 + hi * 8);

#define STAGE_K(dst, jbase)                                                     \
  {                                                                             \
    _Pragma("unroll") for (int i = 0; i < 4; ++i) {                             \
      int c = i * 128 + tid;                                                    \
      int row = c >> 3, kc = c & 7;                                             \
      gload_lds16(kbuf + base + (size_t)((jbase) + row) * 64 + ((kc ^ (row & 7)) << 3), \
                  &(dst)[(i * 128 + wave * 64) * 8]);                           \
    }                                                                           \
  }

  STAGE_K(lK[0], 0);
  __syncthreads();

  floatx16 accA = {}, accB = {};   // O^T[d][i], db = 0 / 1
  float m_ = -1e30f, s_ = 0.f;
  const int bias_off = (i_ - qB) + 1023 - 4 * hi;
  int buf = 0;

  for (int t = 0; t < 16; ++t) {
    const int j0 = t * 64;
    if (t < 15) STAGE_K(lK[buf ^ 1], j0 + 64);

    // V A-frags direct from global (L2-resident): VT[db*32+il][j0 + ks*16 + hi*8 ..]
    bf16x8 vf0[4], vf1[4];
#pragma unroll
    for (int ks = 0; ks < 4; ++ks) {
      vf0[ks] = *(const bf16x8*)(vrow + (size_t)il * 1024 + j0 + ks * 16 + hi * 8);
      vf1[ks] = *(const bf16x8*)(vrow + (size_t)(32 + il) * 1024 + j0 + ks * 16 + hi * 8);
    }

    // QK^T (swapped): st = mfma(K-frag, Q-frag)
    floatx16 st0 = {}, st1 = {};
#pragma unroll
    for (int kd = 0; kd < 4; ++kd) {
      const int kc = ((kd * 2 + hi) ^ (il & 7)) << 3;
      bf16x8 kf0 = *(const bf16x8*)&lK[buf][il * 64 + kc];
      bf16x8 kf1 = *(const bf16x8*)&lK[buf][(32 + il) * 64 + kc];
      st0 = __builtin_amdgcn_mfma_f32_32x32x16_bf16(kf0, qf[kd], st0, 0, 0, 0);
      st1 = __builtin_amdgcn_mfma_f32_32x32x16_bf16(kf1, qf[kd], st1, 0, 0, 0);
    }

    // + relative bias (LDS), track max
    const int bb = bias_off - j0;
    float pm = -1e30f;
#pragma unroll
    for (int r = 0; r < 16; ++r) {
      const int jl = (r & 3) + 8 * (r >> 2);
      st0[r] += lbias[bb - jl];
      st1[r] += lbias[bb - 32 - jl];
      pm = fmaxf(pm, fmaxf(st0[r], st1[r]));
    }
    // full-row max: exchange with lane^32 (shfl_xor: no asm-aliasing hazard)
    pm = fmaxf(pm, __shfl_xor(pm, 32, 64));
    // defer-max (T13): only rescale when max grew by >8 (P bounded by 2^8)
    if (!__all(pm - m_ <= 8.f)) {
      const float nm = fmaxf(m_, pm);
      const float fs = exp2f(m_ - nm);
      s_ *= fs; accA *= fs; accB *= fs;
      m_ = nm;
    }
    // P = exp2(st - m), row-sum
    float rs = 0.f;
#pragma unroll
    for (int r = 0; r < 16; ++r) {
      st0[r] = exp2f(st0[r] - m_);
      st1[r] = exp2f(st1[r] - m_);
      rs += st0[r] + st1[r];
    }
    rs += __shfl_xor(rs, 32, 64);
    s_ += rs;

    // pack P to bf16 pairs: pk[sb][g][e2] = {lo: bf(st[4g+2e2]), hi: bf(st[4g+2e2+1])}
    //   holds P[j-local = 32*sb + 8g + 4*hi_own + 2e2 + {0,1}][i]
    unsigned pk[2][4][2];
#pragma unroll
    for (int g = 0; g < 4; ++g)
#pragma unroll
      for (int e2 = 0; e2 < 2; ++e2) {
        asm("v_cvt_pk_bf16_f32 %0, %1, %2"
            : "=v"(pk[0][g][e2]) : "v"(st0[4 * g + 2 * e2]), "v"(st0[4 * g + 2 * e2 + 1]));
        asm("v_cvt_pk_bf16_f32 %0, %1, %2"
            : "=v"(pk[1][g][e2]) : "v"(st1[4 * g + 2 * e2]), "v"(st1[4 * g + 2 * e2 + 1]));
      }
    // redistribute to PV B-frags via shfl_xor(32) (unambiguous semantics):
    //   pf[ks] element e = P[j-local = 16ks + 8hi + e][i]
    //   dest hi=0: w_lo = own pk[gb],      w_hi = partner pk[gb]
    //   dest hi=1: w_lo = partner pk[gb+1], w_hi = own pk[gb+1]
    bf16x8 pf[4];
#pragma unroll
    for (int ks = 0; ks < 4; ++ks) {
      const int jb = ks >> 1, gb = (ks & 1) * 2;
      uintx4 w;
#pragma unroll
      for (int e2 = 0; e2 < 2; ++e2) {
        unsigned v0 = pk[jb][gb][e2], v1 = pk[jb][gb + 1][e2];
        unsigned send = hi ? v0 : v1;            // what the partner needs
        unsigned recv = __shfl_xor(send, 32, 64);
        w[e2]     = hi ? recv : v0;
        w[2 + e2] = hi ? v1 : recv;
      }
      pf[ks] = *(bf16x8*)&w;
    }

    // PV: O^T[d][i] += V^T[d][j-slice] * P[j-slice][i]
#pragma unroll
    for (int ks = 0; ks < 4; ++ks) {
      accA = __builtin_amdgcn_mfma_f32_32x32x16_bf16(vf0[ks], pf[ks], accA, 0, 0, 0);
      accB = __builtin_amdgcn_mfma_f32_32x32x16_bf16(vf1[ks], pf[ks], accB, 0, 0, 0);
    }

    __syncthreads();  // next K tile staged; all waves done with lK[buf]
    buf ^= 1;
  }

  // epilogue: accA/B reg r -> d = db*32 + (r&3) + 8*(r>>2) + 4*hi, col i_
  const float inv = 1.0f / s_;
  unsigned short* aor = ao + (size_t)(b * 1024 + i_) * 512 + h * 64 + 4 * hi;
#pragma unroll
  for (int rq = 0; rq < 4; ++rq) {
    uint2 u;
    asm("v_cvt_pk_bf16_f32 %0, %1, %2"
        : "=v"(u.x) : "v"(accA[4 * rq] * inv), "v"(accA[4 * rq + 1] * inv));
    asm("v_cvt_pk_bf16_f32 %0, %1, %2"
        : "=v"(u.y) : "v"(accA[4 * rq + 2] * inv), "v"(accA[4 * rq + 3] * inv));
    *(uint2*)(aor + 8 * rq) = u;
    asm("v_cvt_pk_bf16_f32 %0, %1, %2"
        : "=v"(u.x) : "v"(accB[4 * rq] * inv), "v"(accB[4 * rq + 1] * inv));
    asm("v_cvt_pk_bf16_f32 %0, %1, %2"
        : "=v"(u.y) : "v"(accB[4 * rq + 2] * inv), "v"(accB[4 * rq + 3] * inv));
    *(uint2*)(aor + 32 + 8 * rq) = u;
  }
}

// ================= launch =================
extern "C" void kernel_launch(void* const* d_in, const int* in_sizes, int n_in,
                              void* d_out, int out_size, void* d_ws, size_t ws_size,
                              hipStream_t stream) {
  (void)in_sizes; (void)n_in; (void)out_size; (void)ws_size;
  const float* x      = (const float*)d_in[0];  // [8,1024,512]
  const float* w_qkv  = (const float*)d_in[1];  // [512,1536]
  const float* btab   = (const float*)d_in[2];  // [2047,8]
  const float* w_out  = (const float*)d_in[3];  // [512,512]
  const float* b_out  = (const float*)d_in[4];  // [512]
  float* out = (float*)d_out;

  char* ws = (char*)d_ws;
  unsigned short* xb    = (unsigned short*)(ws);             // 8192*512 bf16
  unsigned short* wqkvT = (unsigned short*)(ws + 8388608);   // [1536][512]
  unsigned short* woutT = (unsigned short*)(ws + 9961472);   // [512][512]
  unsigned short* qb    = (unsigned short*)(ws + 10485760);  // [64][1024][64]
  unsigned short* kb    = (unsigned short*)(ws + 18874368);  // [64][1024][64]
  unsigned short* vT    = (unsigned short*)(ws + 27262976);  // [64][64][1024]
  unsigned short* ao    = (unsigned short*)(ws + 35651584);  // [8192][512]
  float*          btT   = (float*)(ws + 44040192);           // [8][2047] f32

  hipLaunchKernelGGL(cast_f32_bf16, dim3(4096), dim3(256), 0, stream, x, xb, 1048576);
  hipLaunchKernelGGL(tcast_f32_bf16, dim3(3072), dim3(256), 0, stream, w_qkv, wqkvT, 512, 1536);
  hipLaunchKernelGGL(tcast_f32_bf16, dim3(1024), dim3(256), 0, stream, w_out, woutT, 512, 512);
  hipLaunchKernelGGL(tbias_kernel, dim3(64), dim3(256), 0, stream, btab, btT);

  hipLaunchKernelGGL((gemm_bf16<0>), dim3(64, 12), dim3(256), 0, stream,
                     xb, wqkvT, 8192, 1536, 512, qb, kb, vT, (float*)nullptr, (const float*)nullptr);

  hipLaunchKernelGGL(attn_kernel, dim3(1024), dim3(128), 0, stream, qb, kb, vT, btT, ao);

  hipLaunchKernelGGL((gemm_bf16<1>), dim3(64, 4), dim3(256), 0, stream,
                     ao, woutT, 8192, 512, 512,
                     (unsigned short*)nullptr, (unsigned short*)nullptr, (unsigned short*)nullptr,
                     out, b_out);
}